// Round 9
// baseline (235.955 us; speedup 1.0000x reference)
//
#include <hip/hip_runtime.h>
#include <math.h>

#define MGT 32
#define NCLS 80
#define TEPS 1e-9f
#define CEPS 1e-7f

// hoisted-precompute CIoU: awh=w1*h1, aatan=atan(w1/(h1+eps)) for box a (gt),
// bwh/batan likewise for box b (pred). Bit-identical to the reference op order.
__device__ __forceinline__ float ciou_pre(float ax1, float ay1, float ax2, float ay2,
                                          float awh, float aatan,
                                          float bx1, float by1, float bx2, float by2,
                                          float bwh, float batan) {
    float iw = fmaxf(fminf(ax2, bx2) - fmaxf(ax1, bx1), 0.f);
    float ih = fmaxf(fminf(ay2, by2) - fmaxf(ay1, by1), 0.f);
    float inter = iw * ih;
    float uni = awh + bwh - inter + CEPS;
    float iou = inter / uni;
    float cw = fmaxf(ax2, bx2) - fminf(ax1, bx1);
    float ch = fmaxf(ay2, by2) - fminf(ay1, by1);
    float c2 = cw * cw + ch * ch + CEPS;
    float dx = bx1 + bx2 - ax1 - ax2;
    float dy = by1 + by2 - ay1 - ay2;
    float rho2 = (dx * dx + dy * dy) * 0.25f;
    float dv = batan - aatan;
    float v = 0.405284734569351f * dv * dv;  // 4/pi^2
    float alpha = v / (v - iou + (1.f + CEPS));
    return iou - (rho2 / c2 + v * alpha);
}

__device__ __forceinline__ float sigm_fast(float x) {
    return __builtin_amdgcn_rcpf(1.f + __expf(-x));
}

// ---- kernel 1: sparse align + per-block top-10 per gt -> pbuf; zero-inits ----
// key = bits(val)<<32 | ~idx : exact (max-val, min-idx) order; 0 = empty.
__global__ __launch_bounds__(256) void k_assign1(const float* __restrict__ cls,
                                                 const float* __restrict__ bdec,
                                                 const float* __restrict__ tgt,
                                                 const float* __restrict__ anc,
                                                 unsigned long long* __restrict__ pbuf,
                                                 unsigned* __restrict__ selmask,
                                                 unsigned* __restrict__ pos_al,
                                                 unsigned* __restrict__ pos_ov,
                                                 int Nv, int gx) {
    __shared__ float sx1[MGT], sy1[MGT], sx2[MGT], sy2[MGT];
    __shared__ float swh[MGT], satan[MGT];
    __shared__ int slab[MGT], svld[MGT];
    __shared__ unsigned long long list[MGT * 10];
    __shared__ unsigned long long wmax[4];
    int b = blockIdx.y, bx = blockIdx.x, tid = threadIdx.x;
    if (tid < MGT) {
        const float* t = tgt + ((size_t)b * MGT + tid) * 5;
        float lf = t[0];
        float x1 = t[1], y1 = t[2], x2 = t[3], y2 = t[4];
        sx1[tid] = x1; sy1[tid] = y1; sx2[tid] = x2; sy2[tid] = y2;
        float gw = x2 - x1, gh = y2 - y1;
        swh[tid] = gw * gh;
        satan[tid] = atanf(gw / (gh + CEPS));
        float area = fmaxf(gw, 0.f) * fmaxf(gh, 0.f);
        int lab = (int)lf;
        svld[tid] = (lab >= 0 && area > 0.f) ? 1 : 0;
        slab[tid] = lab < 0 ? 0 : lab;
        if (bx == 0) {  // zero pos maxes once per batch-row
            pos_al[b * MGT + tid] = 0u;
            pos_ov[b * MGT + tid] = 0u;
        }
    }
    list[tid] = 0ull;
    if (tid < MGT * 10 - 256) list[256 + tid] = 0ull;
    __syncthreads();
    int n = bx * 256 + tid;
    bool valid = n < Nv;
    int nc = valid ? n : (Nv - 1);
    size_t bn = (size_t)b * Nv + nc;
    if (valid) selmask[bn] = 0u;  // stream-ordered before k_merge ORs
    float4 p = reinterpret_cast<const float4*>(bdec)[bn];
    float2 a = reinterpret_cast<const float2*>(anc)[nc];
    const float* crow = cls + bn * NCLS;
    float pw = p.z - p.x, ph = p.w - p.y;
    float pwh = pw * ph;
    float patan = atanf(pw / (ph + CEPS));
    for (int m = 0; m < MGT; ++m) {
        float al = 0.f;
        if (valid && svld[m]) {
            float mn = fminf(fminf(a.x - sx1[m], a.y - sy1[m]),
                             fminf(sx2[m] - a.x, sy2[m] - a.y));
            if (mn > TEPS) {  // sparse: ~2% of pairs reach CIoU
                float ov = fmaxf(ciou_pre(sx1[m], sy1[m], sx2[m], sy2[m],
                                          swh[m], satan[m],
                                          p.x, p.y, p.z, p.w, pwh, patan), 0.f);
                if (ov > 0.f) {
                    float s = sigm_fast(crow[slab[m]]);
                    float o2 = ov * ov;
                    al = __builtin_sqrtf(s) * o2 * o2 * o2;  // s^0.5 * ov^6
                }
            }
        }
        unsigned long long key = (al > 0.f)
            ? ((((unsigned long long)__float_as_uint(al)) << 32) |
               (unsigned)(0xFFFFFFFFu - (unsigned)n))
            : 0ull;
        // block top-10 extraction; round 0 exits immediately for all-zero m
        for (int r = 0; r < 10; ++r) {
            unsigned long long w = key;
#pragma unroll
            for (int s = 32; s > 0; s >>= 1) {
                unsigned long long o = __shfl_xor(w, s, 64);
                w = (o > w) ? o : w;
            }
            if ((tid & 63) == 0) wmax[tid >> 6] = w;
            __syncthreads();
            unsigned long long bw = wmax[0];
            bw = (wmax[1] > bw) ? wmax[1] : bw;
            bw = (wmax[2] > bw) ? wmax[2] : bw;
            bw = (wmax[3] > bw) ? wmax[3] : bw;
            __syncthreads();  // protect wmax before next-round overwrite
            if (bw == 0ull) break;  // uniform
            if (tid == 0) list[m * 10 + r] = bw;
            if (key == bw) key = 0ull;  // unique owner (idx embedded)
        }
    }
    __syncthreads();
    // write per-block lists: pbuf[((b*MGT+m)*gx + bx)*10 + r]
    {
        int t = tid;
        int m = t / 10, r = t - m * 10;
        pbuf[(((size_t)b * MGT + m) * gx + bx) * 10 + r] = list[t];
        t = tid + 256;
        if (t < MGT * 10) {
            m = t / 10; r = t - m * 10;
            pbuf[(((size_t)b * MGT + m) * gx + bx) * 10 + r] = list[t];
        }
    }
}

// ---- kernel 2: merge per-block top-10 lists -> global top-10 -> selmask ----
__global__ __launch_bounds__(256) void k_merge(const unsigned long long* __restrict__ pbuf,
                                               unsigned* __restrict__ selmask,
                                               int Nv, int gx) {
    __shared__ unsigned long long lv[2560];
    __shared__ unsigned long long warp_r[4];
    int bid = blockIdx.x;          // = b*MGT + m
    int b = bid / MGT, m = bid - b * MGT;
    int tid = threadIdx.x;
    const unsigned long long* row = pbuf + (size_t)bid * gx * 10;
    int total = gx * 10;
    unsigned long long v[10];
#pragma unroll
    for (int i = 0; i < 10; ++i) v[i] = 0ull;
    for (int i = tid; i < total; i += 256) {
        unsigned long long key = row[i];
        if (key > v[0]) {
            unsigned long long cv = key; bool placed = false;
#pragma unroll
            for (int j = 0; j < 9; ++j) {
                if (!placed) {
                    if (cv > v[j + 1]) { v[j] = v[j + 1]; }
                    else { v[j] = cv; placed = true; }
                }
            }
            if (!placed) v[9] = cv;
        }
    }
#pragma unroll
    for (int i = 0; i < 10; ++i) lv[tid * 10 + i] = v[i];
    __syncthreads();
    int p = 9;
    for (int r = 0; r < 10; ++r) {
        unsigned long long cand = (p >= 0) ? lv[tid * 10 + p] : 0ull;
        unsigned long long w = cand;
#pragma unroll
        for (int s = 32; s > 0; s >>= 1) {
            unsigned long long o = __shfl_xor(w, s, 64);
            w = (o > w) ? o : w;
        }
        if ((tid & 63) == 0) warp_r[tid >> 6] = w;
        __syncthreads();
        unsigned long long ww = warp_r[0];
        ww = (warp_r[1] > ww) ? warp_r[1] : ww;
        ww = (warp_r[2] > ww) ? warp_r[2] : ww;
        ww = (warp_r[3] > ww) ? warp_r[3] : ww;
        __syncthreads();
        if (ww == 0ull) break;  // uniform: no more candidates
        float wv = __uint_as_float((unsigned)(ww >> 32));
        if (tid == 0 && wv > TEPS) {
            unsigned wi = 0xFFFFFFFFu - (unsigned)(ww & 0xFFFFFFFFull);
            atomicOr(&selmask[(size_t)b * Nv + wi], 1u << m);
        }
        if (p >= 0 && cand == ww) --p;  // unique owner
    }
}

// ---- kernel: resolve multi-assignment (lazy bestm), per-anchor gt/align/ciou ----
__global__ __launch_bounds__(256) void k_resolve(const float* __restrict__ cls,
                                                 const float* __restrict__ bdec,
                                                 const float* __restrict__ tgt,
                                                 const float* __restrict__ anc,
                                                 const unsigned* __restrict__ selmask,
                                                 int* __restrict__ gtf,
                                                 float* __restrict__ amv,
                                                 float* __restrict__ crv,
                                                 unsigned* __restrict__ pos_al,
                                                 unsigned* __restrict__ pos_ov, int Nv) {
    __shared__ float sx1[MGT], sy1[MGT], sx2[MGT], sy2[MGT];
    __shared__ float swh[MGT], satan[MGT];
    __shared__ int slab[MGT], svld[MGT];
    int b = blockIdx.y, tid = threadIdx.x;
    if (tid < MGT) {
        const float* t = tgt + ((size_t)b * MGT + tid) * 5;
        float lf = t[0];
        float x1 = t[1], y1 = t[2], x2 = t[3], y2 = t[4];
        sx1[tid] = x1; sy1[tid] = y1; sx2[tid] = x2; sy2[tid] = y2;
        float gw = x2 - x1, gh = y2 - y1;
        swh[tid] = gw * gh;
        satan[tid] = atanf(gw / (gh + CEPS));
        float area = fmaxf(gw, 0.f) * fmaxf(gh, 0.f);
        int lab = (int)lf;
        svld[tid] = (lab >= 0 && area > 0.f) ? 1 : 0;
        slab[tid] = lab < 0 ? 0 : lab;
    }
    __syncthreads();
    int n = blockIdx.x * 256 + tid;
    if (n >= Nv) return;
    size_t bn = (size_t)b * Nv + n;
    unsigned msk = selmask[bn];
    if (!msk) { gtf[bn] = -1; amv[bn] = 0.f; crv[bn] = 0.f; return; }
    float4 p = reinterpret_cast<const float4*>(bdec)[bn];
    float pw = p.z - p.x, ph = p.w - p.y;
    float pwh = pw * ph;
    float patan = atanf(pw / (ph + CEPS));
    int g;
    if (__popc(msk) > 1) {
        // lazy best = argmax_m clip(ciou,0), first-max tiebreak (unmasked)
        float bo = -1.f; g = 0;
        for (int m = 0; m < MGT; ++m) {
            float ov = fmaxf(ciou_pre(sx1[m], sy1[m], sx2[m], sy2[m],
                                      swh[m], satan[m],
                                      p.x, p.y, p.z, p.w, pwh, patan), 0.f);
            if (ov > bo) { bo = ov; g = m; }
        }
    } else {
        g = __ffs(msk) - 1;
    }
    float cr = ciou_pre(sx1[g], sy1[g], sx2[g], sy2[g], swh[g], satan[g],
                        p.x, p.y, p.z, p.w, pwh, patan);
    float ov = fmaxf(cr, 0.f);
    float al = 0.f;
    if (svld[g]) {
        float2 a = reinterpret_cast<const float2*>(anc)[n];
        float mn = fminf(fminf(a.x - sx1[g], a.y - sy1[g]),
                         fminf(sx2[g] - a.x, sy2[g] - a.y));
        if (mn > TEPS && ov > 0.f) {
            float s = sigm_fast(cls[bn * NCLS + slab[g]]);
            float o2 = ov * ov;
            al = __builtin_sqrtf(s) * o2 * o2 * o2;
        }
    }
    gtf[bn] = g; amv[bn] = al; crv[bn] = cr;
    atomicMax(&pos_al[b * MGT + g], __float_as_uint(al));
    atomicMax(&pos_ov[b * MGT + g], __float_as_uint(ov));
}

// ---- kernel: norm (tval), tlab, tss, IoU loss, DFL loss partials ----
__global__ __launch_bounds__(256) void k_boxdfl(const float* __restrict__ bdist,
                                                const float* __restrict__ tgt,
                                                const float* __restrict__ anc,
                                                const float* __restrict__ strd,
                                                const int* __restrict__ gtf,
                                                const float* __restrict__ amv,
                                                const float* __restrict__ crv,
                                                const unsigned* __restrict__ pos_al,
                                                const unsigned* __restrict__ pos_ov,
                                                float* __restrict__ tval,
                                                int* __restrict__ tlabv,
                                                float* __restrict__ p_tss,
                                                float* __restrict__ p_iou,
                                                float* __restrict__ p_dfl, int Nv) {
    __shared__ float sx1[MGT], sy1[MGT], sx2[MGT], sy2[MGT];
    __shared__ int slab[MGT];
    __shared__ float r0[256], r1[256], r2[256];
    int b = blockIdx.y, tid = threadIdx.x;
    if (tid < MGT) {
        const float* t = tgt + ((size_t)b * MGT + tid) * 5;
        float lf = t[0];
        sx1[tid] = t[1]; sy1[tid] = t[2]; sx2[tid] = t[3]; sy2[tid] = t[4];
        slab[tid] = lf < 0.f ? 0 : (int)lf;
    }
    __syncthreads();
    int n = blockIdx.x * 256 + tid;
    float c_t = 0.f, c_i = 0.f, c_d = 0.f;
    if (n < Nv) {
        size_t bn = (size_t)b * Nv + n;
        int g = gtf[bn];
        float nv = 0.f;
        if (g >= 0) {
            float pa = __uint_as_float(pos_al[b * MGT + g]);
            float po = __uint_as_float(pos_ov[b * MGT + g]);
            nv = amv[bn] * po / (pa + TEPS);
        }
        tval[bn] = nv;
        tlabv[bn] = (g >= 0) ? slab[g] : -1;
        if (nv > 0.f) {
            c_t = nv;
            c_i = (1.f - crv[bn]) * nv;
            float2 a = reinterpret_cast<const float2*>(anc)[n];
            float st = strd[n];
            float ttv[4];
            ttv[0] = (a.x - sx1[g]) / st;
            ttv[1] = (a.y - sy1[g]) / st;
            ttv[2] = (sx2[g] - a.x) / st;
            ttv[3] = (sy2[g] - a.y) / st;
            const float* bd = bdist + bn * 64;
            float acc = 0.f;
#pragma unroll
            for (int k = 0; k < 4; ++k) {
                float t = fminf(fmaxf(ttv[k], 0.f), 14.99f);
                int tl = (int)t;
                float wl = (float)(tl + 1) - t;
                float mx = -3.4e38f;
                for (int j = 0; j < 16; ++j) mx = fmaxf(mx, bd[k * 16 + j]);
                float se = 0.f;
                for (int j = 0; j < 16; ++j) se += __expf(bd[k * 16 + j] - mx);
                float lse = mx + __logf(se);
                float ll = bd[k * 16 + tl] - lse;
                float lr = bd[k * 16 + tl + 1] - lse;
                acc += ll * wl + lr * (1.f - wl);
            }
            c_d = (-acc * 0.25f) * nv;
        }
    }
    r0[tid] = c_t; r1[tid] = c_i; r2[tid] = c_d;
    __syncthreads();
    for (int s = 128; s > 0; s >>= 1) {
        if (tid < s) { r0[tid] += r0[tid + s]; r1[tid] += r1[tid + s]; r2[tid] += r2[tid + s]; }
        __syncthreads();
    }
    if (tid == 0) {
        int bi = blockIdx.y * gridDim.x + blockIdx.x;
        p_tss[bi] = r0[0]; p_iou[bi] = r1[0]; p_dfl[bi] = r2[0];
    }
}

// ---- kernel: BCE classification loss, flat-linear coalesced, fast math ----
__global__ __launch_bounds__(256) void k_cls2(const float* __restrict__ cls,
                                              const int* __restrict__ tlabv,
                                              const float* __restrict__ tval,
                                              float* __restrict__ p_cls,
                                              int total4, int stride_t) {
    __shared__ float rs[256];
    float sum = 0.f;
    for (int i4 = blockIdx.x * 256 + threadIdx.x; i4 < total4; i4 += stride_t) {
        int bn = i4 / 20;  // 20 float4 per 80-class row
        int pos = i4 - bn * 20;
        float4 x4 = reinterpret_cast<const float4*>(cls)[i4];
        int tlab = tlabv[bn];
        float tv = tval[bn];
        int c0 = pos * 4;
        float xs[4] = {x4.x, x4.y, x4.z, x4.w};
#pragma unroll
        for (int e = 0; e < 4; ++e) {
            float x = xs[e];
            float ea = __expf(-fabsf(x));        // shared: sigmoid + log1p
            float r = __builtin_amdgcn_rcpf(1.f + ea);
            float p = (x >= 0.f) ? r : ea * r;   // sigmoid(x)
            float t = (c0 + e == tlab) ? tv : 0.f;
            float bce = fmaxf(x, 0.f) - x * t + __logf(1.f + ea);
            float w = (t > 0.f) ? t : 0.75f * p * p;
            sum += bce * w;
        }
    }
    rs[threadIdx.x] = sum;
    __syncthreads();
    for (int s = 128; s > 0; s >>= 1) {
        if (threadIdx.x < s) rs[threadIdx.x] += rs[threadIdx.x + s];
        __syncthreads();
    }
    if (threadIdx.x == 0) p_cls[blockIdx.x] = rs[0];
}

// ---- kernel: deterministic final reduce + combine ----
__global__ __launch_bounds__(256) void k_final(const float* __restrict__ p_tss,
                                               const float* __restrict__ p_iou,
                                               const float* __restrict__ p_dfl,
                                               int nb,
                                               const float* __restrict__ p_cls,
                                               int ncb, float* __restrict__ out, int Bv) {
    __shared__ float s0[256], s1[256], s2[256], s3[256];
    int tid = threadIdx.x;
    float a0 = 0.f, a1 = 0.f, a2 = 0.f, a3 = 0.f;
    for (int i = tid; i < nb; i += 256) {
        a0 += p_tss[i]; a1 += p_iou[i]; a2 += p_dfl[i];
    }
    for (int i = tid; i < ncb; i += 256) a3 += p_cls[i];
    s0[tid] = a0; s1[tid] = a1; s2[tid] = a2; s3[tid] = a3;
    __syncthreads();
    for (int s = 128; s > 0; s >>= 1) {
        if (tid < s) { s0[tid] += s0[tid + s]; s1[tid] += s1[tid + s];
                       s2[tid] += s2[tid + s]; s3[tid] += s3[tid + s]; }
        __syncthreads();
    }
    if (tid == 0) {
        float tss = fmaxf(s0[0], 1.f);
        float lcls = 0.5f * s3[0] / tss;
        float liou = 7.5f * s1[0] / tss;
        float ldfl = 1.5f * s2[0] / tss;
        out[0] = (lcls + liou + ldfl) * (float)Bv;
        out[1] = lcls;
        out[2] = liou;
        out[3] = ldfl;
    }
}

extern "C" void kernel_launch(void* const* d_in, const int* in_sizes, int n_in,
                              void* d_out, int out_size, void* d_ws, size_t ws_size,
                              hipStream_t stream) {
    const float* cls = (const float*)d_in[0];
    const float* bdist = (const float*)d_in[1];
    const float* bdec = (const float*)d_in[2];
    const float* tgt = (const float*)d_in[3];
    const float* anc = (const float*)d_in[4];
    const float* strd = (const float*)d_in[5];
    int Nv = in_sizes[4] / 2;
    int Bv = in_sizes[3] / (MGT * 5);
    size_t nBN = (size_t)Bv * Nv;
    int gx = (Nv + 255) / 256;
    int nb = gx * Bv;
    int total4 = (int)(nBN * (NCLS / 4));
    int ncb = 2048;
    if ((long long)ncb * 256 > (long long)total4) ncb = (total4 + 255) / 256;

    char* base = (char*)d_ws;
    size_t off = 0;
    unsigned* selmask = (unsigned*)(base + off); off += nBN * 4;
    unsigned* pos_al = (unsigned*)(base + off); off += (size_t)Bv * MGT * 4;
    unsigned* pos_ov = (unsigned*)(base + off); off += (size_t)Bv * MGT * 4;
    unsigned long long* pbuf = (unsigned long long*)(base + off);
    off += (size_t)Bv * MGT * gx * 10 * 8;
    int* gtfv = (int*)(base + off); off += nBN * 4;
    float* amv = (float*)(base + off); off += nBN * 4;
    float* crvv = (float*)(base + off); off += nBN * 4;
    float* tvalv = (float*)(base + off); off += nBN * 4;
    int* tlabv = (int*)(base + off); off += nBN * 4;
    float* p_tss = (float*)(base + off); off += (size_t)nb * 4;
    float* p_iou = (float*)(base + off); off += (size_t)nb * 4;
    float* p_dfl = (float*)(base + off); off += (size_t)nb * 4;
    float* p_cls = (float*)(base + off); off += (size_t)ncb * 4;

    dim3 grid(gx, Bv);
    k_assign1<<<grid, 256, 0, stream>>>(cls, bdec, tgt, anc, pbuf,
                                        selmask, pos_al, pos_ov, Nv, gx);
    k_merge<<<Bv * MGT, 256, 0, stream>>>(pbuf, selmask, Nv, gx);
    k_resolve<<<grid, 256, 0, stream>>>(cls, bdec, tgt, anc, selmask,
                                        gtfv, amv, crvv, pos_al, pos_ov, Nv);
    k_boxdfl<<<grid, 256, 0, stream>>>(bdist, tgt, anc, strd, gtfv, amv, crvv,
                                       pos_al, pos_ov, tvalv, tlabv,
                                       p_tss, p_iou, p_dfl, Nv);
    k_cls2<<<ncb, 256, 0, stream>>>(cls, tlabv, tvalv, p_cls, total4, ncb * 256);
    k_final<<<1, 256, 0, stream>>>(p_tss, p_iou, p_dfl, nb, p_cls, ncb,
                                   (float*)d_out, Bv);
}

// Round 10
// 159.896 us; speedup vs baseline: 1.4757x; 1.4757x over previous
//
#include <hip/hip_runtime.h>
#include <math.h>

#define MGT 32
#define NCLS 80
#define TEPS 1e-9f
#define CEPS 1e-7f

// hoisted-precompute CIoU: awh=w1*h1, aatan=atan(w1/(h1+eps)) for box a (gt),
// bwh/batan likewise for box b (pred). Bit-identical to the reference op order.
__device__ __forceinline__ float ciou_pre(float ax1, float ay1, float ax2, float ay2,
                                          float awh, float aatan,
                                          float bx1, float by1, float bx2, float by2,
                                          float bwh, float batan) {
    float iw = fmaxf(fminf(ax2, bx2) - fmaxf(ax1, bx1), 0.f);
    float ih = fmaxf(fminf(ay2, by2) - fmaxf(ay1, by1), 0.f);
    float inter = iw * ih;
    float uni = awh + bwh - inter + CEPS;
    float iou = inter / uni;
    float cw = fmaxf(ax2, bx2) - fminf(ax1, bx1);
    float ch = fmaxf(ay2, by2) - fminf(ay1, by1);
    float c2 = cw * cw + ch * ch + CEPS;
    float dx = bx1 + bx2 - ax1 - ax2;
    float dy = by1 + by2 - ay1 - ay2;
    float rho2 = (dx * dx + dy * dy) * 0.25f;
    float dv = batan - aatan;
    float v = 0.405284734569351f * dv * dv;  // 4/pi^2
    float alpha = v / (v - iou + (1.f + CEPS));
    return iou - (rho2 / c2 + v * alpha);
}

__device__ __forceinline__ float sigm_fast(float x) {
    return __builtin_amdgcn_rcpf(1.f + __expf(-x));
}

// ---- kernel: sparse align (CIoU only in-box) -> dense abuf; zero-inits folded ----
__global__ __launch_bounds__(256) void k_align(const float* __restrict__ cls,
                                               const float* __restrict__ bdec,
                                               const float* __restrict__ tgt,
                                               const float* __restrict__ anc,
                                               float* __restrict__ abuf,
                                               unsigned* __restrict__ selmask,
                                               unsigned* __restrict__ pos_al,
                                               unsigned* __restrict__ pos_ov,
                                               int cs, int clen, int Nv) {
    __shared__ float sx1[MGT], sy1[MGT], sx2[MGT], sy2[MGT];
    __shared__ float swh[MGT], satan[MGT];
    __shared__ int slab[MGT], svld[MGT];
    int b = blockIdx.y, tid = threadIdx.x;
    if (tid < MGT) {
        const float* t = tgt + ((size_t)b * MGT + tid) * 5;
        float lf = t[0];
        float x1 = t[1], y1 = t[2], x2 = t[3], y2 = t[4];
        sx1[tid] = x1; sy1[tid] = y1; sx2[tid] = x2; sy2[tid] = y2;
        float gw = x2 - x1, gh = y2 - y1;
        swh[tid] = gw * gh;
        satan[tid] = atanf(gw / (gh + CEPS));
        float area = fmaxf(gw, 0.f) * fmaxf(gh, 0.f);
        int lab = (int)lf;
        svld[tid] = (lab >= 0 && area > 0.f) ? 1 : 0;
        slab[tid] = lab < 0 ? 0 : lab;
        if (blockIdx.x == 0 && cs == 0) {  // zero pos maxes once per batch-row
            pos_al[b * MGT + tid] = 0u;
            pos_ov[b * MGT + tid] = 0u;
        }
    }
    __syncthreads();
    int n = blockIdx.x * 256 + tid;
    if (n >= Nv) return;
    size_t bn = (size_t)b * Nv + n;
    if (cs == 0) selmask[bn] = 0u;  // stream-ordered before k_topk ORs
    float4 p = reinterpret_cast<const float4*>(bdec)[bn];
    float2 a = reinterpret_cast<const float2*>(anc)[n];
    const float* crow = cls + bn * NCLS;
    float pw = p.z - p.x, ph = p.w - p.y;
    float pwh = pw * ph;
    float patan = atanf(pw / (ph + CEPS));
    for (int mm = 0; mm < clen; ++mm) {
        int m = cs + mm;
        float al = 0.f;
        if (svld[m]) {
            float mn = fminf(fminf(a.x - sx1[m], a.y - sy1[m]),
                             fminf(sx2[m] - a.x, sy2[m] - a.y));
            if (mn > TEPS) {  // sparse: ~2% of pairs reach CIoU
                float ov = fmaxf(ciou_pre(sx1[m], sy1[m], sx2[m], sy2[m],
                                          swh[m], satan[m],
                                          p.x, p.y, p.z, p.w, pwh, patan), 0.f);
                if (ov > 0.f) {
                    float s = sigm_fast(crow[slab[m]]);
                    float o2 = ov * ov;
                    al = __builtin_sqrtf(s) * o2 * o2 * o2;  // s^0.5 * ov^6
                }
            }
        }
        abuf[((size_t)b * clen + mm) * Nv + n] = al;
    }
}

// ---- kernel: per-(b,m) top-10 over N via u64 keys + wave shuffle reduce ----
// key = bits(val)<<32 | ~idx  (monotone for val>0): max-val, then min-idx tiebreak.
__global__ __launch_bounds__(256) void k_topk(const float* __restrict__ abuf,
                                              unsigned* __restrict__ selmask,
                                              int cs, int clen, int Nv) {
    __shared__ unsigned long long lv[2560];
    __shared__ unsigned long long warp_r[4];
    __shared__ unsigned long long winner_s;
    int bmi = blockIdx.x;
    int b = bmi / clen, mm = bmi % clen;
    int m = cs + mm;
    int tid = threadIdx.x;
    const float* row = abuf + ((size_t)b * clen + mm) * Nv;
    unsigned long long v[10];
#pragma unroll
    for (int i = 0; i < 10; ++i) v[i] = 0ull;
    for (int n = tid; n < Nv; n += 256) {
        float aa = row[n];
        if (aa > 0.f) {
            unsigned long long key =
                (((unsigned long long)__float_as_uint(aa)) << 32) |
                (unsigned)(0xFFFFFFFFu - (unsigned)n);
            if (key > v[0]) {  // sorted ascending insert
                unsigned long long cv = key; bool placed = false;
#pragma unroll
                for (int i = 0; i < 9; ++i) {
                    if (!placed) {
                        if (cv > v[i + 1]) { v[i] = v[i + 1]; }
                        else { v[i] = cv; placed = true; }
                    }
                }
                if (!placed) v[9] = cv;
            }
        }
    }
#pragma unroll
    for (int i = 0; i < 10; ++i) lv[tid * 10 + i] = v[i];
    __syncthreads();
    int p = 9;
    for (int r = 0; r < 10; ++r) {
        unsigned long long cand = (p >= 0) ? lv[tid * 10 + p] : 0ull;
        unsigned long long w = cand;
#pragma unroll
        for (int s = 32; s > 0; s >>= 1) {
            unsigned long long o = __shfl_xor(w, s, 64);
            w = (o > w) ? o : w;
        }
        if ((tid & 63) == 0) warp_r[tid >> 6] = w;
        __syncthreads();
        if (tid == 0) {
            unsigned long long ww = warp_r[0];
            ww = (warp_r[1] > ww) ? warp_r[1] : ww;
            ww = (warp_r[2] > ww) ? warp_r[2] : ww;
            ww = (warp_r[3] > ww) ? warp_r[3] : ww;
            winner_s = ww;
            float wv = __uint_as_float((unsigned)(ww >> 32));
            if (wv > TEPS) {
                unsigned wi = 0xFFFFFFFFu - (unsigned)(ww & 0xFFFFFFFFull);
                atomicOr(&selmask[(size_t)b * Nv + wi], 1u << m);
            }
        }
        __syncthreads();
        unsigned long long win = winner_s;
        if (win == 0ull) break;  // no more positive candidates anywhere
        if (p >= 0 && cand == win) --p;  // unique owner (idx embedded in key)
        __syncthreads();
    }
}

// ---- kernel: resolve multi-assignment (lazy bestm), per-anchor gt/align/ciou ----
__global__ __launch_bounds__(256) void k_resolve(const float* __restrict__ cls,
                                                 const float* __restrict__ bdec,
                                                 const float* __restrict__ tgt,
                                                 const float* __restrict__ anc,
                                                 const unsigned* __restrict__ selmask,
                                                 int* __restrict__ gtf,
                                                 float* __restrict__ amv,
                                                 float* __restrict__ crv,
                                                 unsigned* __restrict__ pos_al,
                                                 unsigned* __restrict__ pos_ov, int Nv) {
    __shared__ float sx1[MGT], sy1[MGT], sx2[MGT], sy2[MGT];
    __shared__ float swh[MGT], satan[MGT];
    __shared__ int slab[MGT], svld[MGT];
    int b = blockIdx.y, tid = threadIdx.x;
    if (tid < MGT) {
        const float* t = tgt + ((size_t)b * MGT + tid) * 5;
        float lf = t[0];
        float x1 = t[1], y1 = t[2], x2 = t[3], y2 = t[4];
        sx1[tid] = x1; sy1[tid] = y1; sx2[tid] = x2; sy2[tid] = y2;
        float gw = x2 - x1, gh = y2 - y1;
        swh[tid] = gw * gh;
        satan[tid] = atanf(gw / (gh + CEPS));
        float area = fmaxf(gw, 0.f) * fmaxf(gh, 0.f);
        int lab = (int)lf;
        svld[tid] = (lab >= 0 && area > 0.f) ? 1 : 0;
        slab[tid] = lab < 0 ? 0 : lab;
    }
    __syncthreads();
    int n = blockIdx.x * 256 + tid;
    if (n >= Nv) return;
    size_t bn = (size_t)b * Nv + n;
    unsigned msk = selmask[bn];
    if (!msk) { gtf[bn] = -1; amv[bn] = 0.f; crv[bn] = 0.f; return; }
    float4 p = reinterpret_cast<const float4*>(bdec)[bn];
    float pw = p.z - p.x, ph = p.w - p.y;
    float pwh = pw * ph;
    float patan = atanf(pw / (ph + CEPS));
    int g;
    if (__popc(msk) > 1) {
        // lazy best = argmax_m clip(ciou,0), first-max tiebreak (unmasked)
        float bo = -1.f; g = 0;
        for (int m = 0; m < MGT; ++m) {
            float ov = fmaxf(ciou_pre(sx1[m], sy1[m], sx2[m], sy2[m],
                                      swh[m], satan[m],
                                      p.x, p.y, p.z, p.w, pwh, patan), 0.f);
            if (ov > bo) { bo = ov; g = m; }
        }
    } else {
        g = __ffs(msk) - 1;
    }
    float cr = ciou_pre(sx1[g], sy1[g], sx2[g], sy2[g], swh[g], satan[g],
                        p.x, p.y, p.z, p.w, pwh, patan);
    float ov = fmaxf(cr, 0.f);
    float al = 0.f;
    if (svld[g]) {
        float2 a = reinterpret_cast<const float2*>(anc)[n];
        float mn = fminf(fminf(a.x - sx1[g], a.y - sy1[g]),
                         fminf(sx2[g] - a.x, sy2[g] - a.y));
        if (mn > TEPS && ov > 0.f) {
            float s = sigm_fast(cls[bn * NCLS + slab[g]]);
            float o2 = ov * ov;
            al = __builtin_sqrtf(s) * o2 * o2 * o2;
        }
    }
    gtf[bn] = g; amv[bn] = al; crv[bn] = cr;
    atomicMax(&pos_al[b * MGT + g], __float_as_uint(al));
    atomicMax(&pos_ov[b * MGT + g], __float_as_uint(ov));
}

// ---- kernel: norm (tval), tlab, tss, IoU loss, DFL loss partials ----
__global__ __launch_bounds__(256) void k_boxdfl(const float* __restrict__ bdist,
                                                const float* __restrict__ tgt,
                                                const float* __restrict__ anc,
                                                const float* __restrict__ strd,
                                                const int* __restrict__ gtf,
                                                const float* __restrict__ amv,
                                                const float* __restrict__ crv,
                                                const unsigned* __restrict__ pos_al,
                                                const unsigned* __restrict__ pos_ov,
                                                float* __restrict__ tval,
                                                int* __restrict__ tlabv,
                                                float* __restrict__ p_tss,
                                                float* __restrict__ p_iou,
                                                float* __restrict__ p_dfl, int Nv) {
    __shared__ float sx1[MGT], sy1[MGT], sx2[MGT], sy2[MGT];
    __shared__ int slab[MGT];
    __shared__ float r0[256], r1[256], r2[256];
    int b = blockIdx.y, tid = threadIdx.x;
    if (tid < MGT) {
        const float* t = tgt + ((size_t)b * MGT + tid) * 5;
        float lf = t[0];
        sx1[tid] = t[1]; sy1[tid] = t[2]; sx2[tid] = t[3]; sy2[tid] = t[4];
        slab[tid] = lf < 0.f ? 0 : (int)lf;
    }
    __syncthreads();
    int n = blockIdx.x * 256 + tid;
    float c_t = 0.f, c_i = 0.f, c_d = 0.f;
    if (n < Nv) {
        size_t bn = (size_t)b * Nv + n;
        int g = gtf[bn];
        float nv = 0.f;
        if (g >= 0) {
            float pa = __uint_as_float(pos_al[b * MGT + g]);
            float po = __uint_as_float(pos_ov[b * MGT + g]);
            nv = amv[bn] * po / (pa + TEPS);
        }
        tval[bn] = nv;
        tlabv[bn] = (g >= 0) ? slab[g] : -1;
        if (nv > 0.f) {
            c_t = nv;
            c_i = (1.f - crv[bn]) * nv;
            float2 a = reinterpret_cast<const float2*>(anc)[n];
            float st = strd[n];
            float ttv[4];
            ttv[0] = (a.x - sx1[g]) / st;
            ttv[1] = (a.y - sy1[g]) / st;
            ttv[2] = (sx2[g] - a.x) / st;
            ttv[3] = (sy2[g] - a.y) / st;
            const float* bd = bdist + bn * 64;
            float acc = 0.f;
#pragma unroll
            for (int k = 0; k < 4; ++k) {
                float t = fminf(fmaxf(ttv[k], 0.f), 14.99f);
                int tl = (int)t;
                float wl = (float)(tl + 1) - t;
                float mx = -3.4e38f;
                for (int j = 0; j < 16; ++j) mx = fmaxf(mx, bd[k * 16 + j]);
                float se = 0.f;
                for (int j = 0; j < 16; ++j) se += __expf(bd[k * 16 + j] - mx);
                float lse = mx + __logf(se);
                float ll = bd[k * 16 + tl] - lse;
                float lr = bd[k * 16 + tl + 1] - lse;
                acc += ll * wl + lr * (1.f - wl);
            }
            c_d = (-acc * 0.25f) * nv;
        }
    }
    r0[tid] = c_t; r1[tid] = c_i; r2[tid] = c_d;
    __syncthreads();
    for (int s = 128; s > 0; s >>= 1) {
        if (tid < s) { r0[tid] += r0[tid + s]; r1[tid] += r1[tid + s]; r2[tid] += r2[tid + s]; }
        __syncthreads();
    }
    if (tid == 0) {
        int bi = blockIdx.y * gridDim.x + blockIdx.x;
        p_tss[bi] = r0[0]; p_iou[bi] = r1[0]; p_dfl[bi] = r2[0];
    }
}

// ---- kernel: BCE classification loss, flat-linear coalesced, fast math ----
__global__ __launch_bounds__(256) void k_cls2(const float* __restrict__ cls,
                                              const int* __restrict__ tlabv,
                                              const float* __restrict__ tval,
                                              float* __restrict__ p_cls,
                                              int total4, int stride_t) {
    __shared__ float rs[256];
    float sum = 0.f;
    for (int i4 = blockIdx.x * 256 + threadIdx.x; i4 < total4; i4 += stride_t) {
        int bn = i4 / 20;  // 20 float4 per 80-class row
        int pos = i4 - bn * 20;
        float4 x4 = reinterpret_cast<const float4*>(cls)[i4];
        int tlab = tlabv[bn];
        float tv = tval[bn];
        int c0 = pos * 4;
        float xs[4] = {x4.x, x4.y, x4.z, x4.w};
#pragma unroll
        for (int e = 0; e < 4; ++e) {
            float x = xs[e];
            float ea = __expf(-fabsf(x));        // shared: sigmoid + log1p
            float r = __builtin_amdgcn_rcpf(1.f + ea);
            float p = (x >= 0.f) ? r : ea * r;   // sigmoid(x)
            float t = (c0 + e == tlab) ? tv : 0.f;
            float bce = fmaxf(x, 0.f) - x * t + __logf(1.f + ea);
            float w = (t > 0.f) ? t : 0.75f * p * p;
            sum += bce * w;
        }
    }
    rs[threadIdx.x] = sum;
    __syncthreads();
    for (int s = 128; s > 0; s >>= 1) {
        if (threadIdx.x < s) rs[threadIdx.x] += rs[threadIdx.x + s];
        __syncthreads();
    }
    if (threadIdx.x == 0) p_cls[blockIdx.x] = rs[0];
}

// ---- kernel: deterministic final reduce + combine ----
__global__ __launch_bounds__(256) void k_final(const float* __restrict__ p_tss,
                                               const float* __restrict__ p_iou,
                                               const float* __restrict__ p_dfl,
                                               int nb,
                                               const float* __restrict__ p_cls,
                                               int ncb, float* __restrict__ out, int Bv) {
    __shared__ float s0[256], s1[256], s2[256], s3[256];
    int tid = threadIdx.x;
    float a0 = 0.f, a1 = 0.f, a2 = 0.f, a3 = 0.f;
    for (int i = tid; i < nb; i += 256) {
        a0 += p_tss[i]; a1 += p_iou[i]; a2 += p_dfl[i];
    }
    for (int i = tid; i < ncb; i += 256) a3 += p_cls[i];
    s0[tid] = a0; s1[tid] = a1; s2[tid] = a2; s3[tid] = a3;
    __syncthreads();
    for (int s = 128; s > 0; s >>= 1) {
        if (tid < s) { s0[tid] += s0[tid + s]; s1[tid] += s1[tid + s];
                       s2[tid] += s2[tid + s]; s3[tid] += s3[tid + s]; }
        __syncthreads();
    }
    if (tid == 0) {
        float tss = fmaxf(s0[0], 1.f);
        float lcls = 0.5f * s3[0] / tss;
        float liou = 7.5f * s1[0] / tss;
        float ldfl = 1.5f * s2[0] / tss;
        out[0] = (lcls + liou + ldfl) * (float)Bv;
        out[1] = lcls;
        out[2] = liou;
        out[3] = ldfl;
    }
}

extern "C" void kernel_launch(void* const* d_in, const int* in_sizes, int n_in,
                              void* d_out, int out_size, void* d_ws, size_t ws_size,
                              hipStream_t stream) {
    const float* cls = (const float*)d_in[0];
    const float* bdist = (const float*)d_in[1];
    const float* bdec = (const float*)d_in[2];
    const float* tgt = (const float*)d_in[3];
    const float* anc = (const float*)d_in[4];
    const float* strd = (const float*)d_in[5];
    int Nv = in_sizes[4] / 2;
    int Bv = in_sizes[3] / (MGT * 5);
    size_t nBN = (size_t)Bv * Nv;
    int gx = (Nv + 255) / 256;
    int nb = gx * Bv;
    int total4 = (int)(nBN * (NCLS / 4));
    int ncb = 2048;
    if ((long long)ncb * 256 > (long long)total4) ncb = (total4 + 255) / 256;

    char* base = (char*)d_ws;
    size_t off = 0;
    unsigned* selmask = (unsigned*)(base + off); off += nBN * 4;
    unsigned* pos_al = (unsigned*)(base + off); off += (size_t)Bv * MGT * 4;
    unsigned* pos_ov = (unsigned*)(base + off); off += (size_t)Bv * MGT * 4;
    int* gtfv = (int*)(base + off); off += nBN * 4;
    float* amv = (float*)(base + off); off += nBN * 4;
    float* crvv = (float*)(base + off); off += nBN * 4;
    float* tvalv = (float*)(base + off); off += nBN * 4;
    int* tlabv = (int*)(base + off); off += nBN * 4;
    float* p_tss = (float*)(base + off); off += (size_t)nb * 4;
    float* p_iou = (float*)(base + off); off += (size_t)nb * 4;
    float* p_dfl = (float*)(base + off); off += (size_t)nb * 4;
    float* p_cls = (float*)(base + off); off += (size_t)ncb * 4;
    float* abuf = (float*)(base + off);
    size_t remain = (ws_size > off) ? (ws_size - off) : 0;
    int chunk = (int)(remain / (nBN * 4));
    if (chunk > MGT) chunk = MGT;
    if (chunk < 1) chunk = 1;

    dim3 grid(gx, Bv);
    for (int cs = 0; cs < MGT; cs += chunk) {
        int clen = (MGT - cs < chunk) ? (MGT - cs) : chunk;
        k_align<<<grid, 256, 0, stream>>>(cls, bdec, tgt, anc, abuf,
                                          selmask, pos_al, pos_ov, cs, clen, Nv);
        k_topk<<<Bv * clen, 256, 0, stream>>>(abuf, selmask, cs, clen, Nv);
    }
    k_resolve<<<grid, 256, 0, stream>>>(cls, bdec, tgt, anc, selmask,
                                        gtfv, amv, crvv, pos_al, pos_ov, Nv);
    k_boxdfl<<<grid, 256, 0, stream>>>(bdist, tgt, anc, strd, gtfv, amv, crvv,
                                       pos_al, pos_ov, tvalv, tlabv,
                                       p_tss, p_iou, p_dfl, Nv);
    k_cls2<<<ncb, 256, 0, stream>>>(cls, tlabv, tvalv, p_cls, total4, ncb * 256);
    k_final<<<1, 256, 0, stream>>>(p_tss, p_iou, p_dfl, nb, p_cls, ncb,
                                   (float*)d_out, Bv);
}

// Round 12
// 120.996 us; speedup vs baseline: 1.9501x; 1.3215x over previous
//
#include <hip/hip_runtime.h>
#include <math.h>

#define MGT 32
#define NCLS 80
#define TEPS 1e-9f
#define CEPS 1e-7f
#define CAPMAX 4096

// hoisted-precompute CIoU: awh=w1*h1, aatan=atan(w1/(h1+eps)) for box a (gt),
// bwh/batan likewise for box b (pred). Bit-identical to the reference op order.
__device__ __forceinline__ float ciou_pre(float ax1, float ay1, float ax2, float ay2,
                                          float awh, float aatan,
                                          float bx1, float by1, float bx2, float by2,
                                          float bwh, float batan) {
    float iw = fmaxf(fminf(ax2, bx2) - fmaxf(ax1, bx1), 0.f);
    float ih = fmaxf(fminf(ay2, by2) - fmaxf(ay1, by1), 0.f);
    float inter = iw * ih;
    float uni = awh + bwh - inter + CEPS;
    float iou = inter / uni;
    float cw = fmaxf(ax2, bx2) - fminf(ax1, bx1);
    float ch = fmaxf(ay2, by2) - fminf(ay1, by1);
    float c2 = cw * cw + ch * ch + CEPS;
    float dx = bx1 + bx2 - ax1 - ax2;
    float dy = by1 + by2 - ay1 - ay2;
    float rho2 = (dx * dx + dy * dy) * 0.25f;
    float dv = batan - aatan;
    float v = 0.405284734569351f * dv * dv;  // 4/pi^2
    float alpha = v / (v - iou + (1.f + CEPS));
    return iou - (rho2 / c2 + v * alpha);
}

__device__ __forceinline__ float sigm_fast(float x) {
    return __builtin_amdgcn_rcpf(1.f + __expf(-x));
}

// ---- kernel: sparse align -> compact per-(b,m) candidate lists; zero-inits ----
// key = bits(al)<<32 | ~n : exact (max-val, min-idx) order; only al>0 appended.
__global__ __launch_bounds__(256) void k_cand(const float* __restrict__ cls,
                                              const float* __restrict__ bdec,
                                              const float* __restrict__ tgt,
                                              const float* __restrict__ anc,
                                              unsigned long long* __restrict__ cand,
                                              unsigned* __restrict__ cnt,
                                              unsigned* __restrict__ selmask,
                                              unsigned* __restrict__ pos_al,
                                              unsigned* __restrict__ pos_ov,
                                              int Nv, int cap) {
    __shared__ float sx1[MGT], sy1[MGT], sx2[MGT], sy2[MGT];
    __shared__ float swh[MGT], satan[MGT];
    __shared__ int slab[MGT], svld[MGT];
    int b = blockIdx.y, tid = threadIdx.x;
    if (tid < MGT) {
        const float* t = tgt + ((size_t)b * MGT + tid) * 5;
        float lf = t[0];
        float x1 = t[1], y1 = t[2], x2 = t[3], y2 = t[4];
        sx1[tid] = x1; sy1[tid] = y1; sx2[tid] = x2; sy2[tid] = y2;
        float gw = x2 - x1, gh = y2 - y1;
        swh[tid] = gw * gh;
        satan[tid] = atanf(gw / (gh + CEPS));
        float area = fmaxf(gw, 0.f) * fmaxf(gh, 0.f);
        int lab = (int)lf;
        svld[tid] = (lab >= 0 && area > 0.f) ? 1 : 0;
        slab[tid] = lab < 0 ? 0 : lab;
        if (blockIdx.x == 0) {  // zero pos maxes once per batch-row
            pos_al[b * MGT + tid] = 0u;
            pos_ov[b * MGT + tid] = 0u;
        }
    }
    __syncthreads();
    int n = blockIdx.x * 256 + tid;
    if (n >= Nv) return;
    size_t bn = (size_t)b * Nv + n;
    selmask[bn] = 0u;  // stream-ordered before k_topk2 ORs
    float4 p = reinterpret_cast<const float4*>(bdec)[bn];
    float2 a = reinterpret_cast<const float2*>(anc)[n];
    const float* crow = cls + bn * NCLS;
    float pw = p.z - p.x, ph = p.w - p.y;
    float pwh = pw * ph;
    float patan = 0.f; bool have_patan = false;
    int lane = tid & 63;
    for (int m = 0; m < MGT; ++m) {
        float al = 0.f;
        if (svld[m]) {
            float mn = fminf(fminf(a.x - sx1[m], a.y - sy1[m]),
                             fminf(sx2[m] - a.x, sy2[m] - a.y));
            if (mn > TEPS) {  // sparse: ~2% of pairs reach CIoU
                if (!have_patan) { patan = atanf(pw / (ph + CEPS)); have_patan = true; }
                float ov = fmaxf(ciou_pre(sx1[m], sy1[m], sx2[m], sy2[m],
                                          swh[m], satan[m],
                                          p.x, p.y, p.z, p.w, pwh, patan), 0.f);
                if (ov > 0.f) {
                    float s = sigm_fast(crow[slab[m]]);
                    float o2 = ov * ov;
                    al = __builtin_sqrtf(s) * o2 * o2 * o2;  // s^0.5 * ov^6
                }
            }
        }
        // wave-aggregated append (order within list is irrelevant: set semantics)
        unsigned long long msk = __ballot(al > 0.f);
        if (msk) {
            int leader = __ffsll((long long)msk) - 1;
            unsigned base = 0;
            if (lane == leader)
                base = atomicAdd(&cnt[b * MGT + m], (unsigned)__popcll(msk));
            base = __shfl(base, leader, 64);
            if (al > 0.f) {
                unsigned rank = (unsigned)__popcll(msk & ((1ull << lane) - 1ull));
                unsigned idx = base + rank;
                if ((int)idx < cap) {
                    unsigned long long key =
                        (((unsigned long long)__float_as_uint(al)) << 32) |
                        (unsigned)(0xFFFFFFFFu - (unsigned)n);
                    cand[((size_t)b * MGT + m) * cap + idx] = key;
                }
            }
        }
    }
}

// ---- kernel: per-(b,m) top-10 from compact list -> selmask ----
__global__ __launch_bounds__(256) void k_topk2(const unsigned long long* __restrict__ cand,
                                               const unsigned* __restrict__ cnt,
                                               unsigned* __restrict__ selmask,
                                               int Nv, int cap) {
    __shared__ unsigned long long lv[2560];
    __shared__ unsigned long long warp_r[4];
    __shared__ unsigned long long winner_s;
    int bid = blockIdx.x;          // = b*MGT + m
    int b = bid / MGT, m = bid - b * MGT;
    int tid = threadIdx.x;
    int total = (int)cnt[bid];
    if (total > cap) total = cap;
    const unsigned long long* row = cand + (size_t)bid * cap;
    unsigned long long v[10];
#pragma unroll
    for (int i = 0; i < 10; ++i) v[i] = 0ull;
    for (int i = tid; i < total; i += 256) {
        unsigned long long key = row[i];
        if (key > v[0]) {  // sorted ascending insert
            unsigned long long cv = key; bool placed = false;
#pragma unroll
            for (int j = 0; j < 9; ++j) {
                if (!placed) {
                    if (cv > v[j + 1]) { v[j] = v[j + 1]; }
                    else { v[j] = cv; placed = true; }
                }
            }
            if (!placed) v[9] = cv;
        }
    }
#pragma unroll
    for (int i = 0; i < 10; ++i) lv[tid * 10 + i] = v[i];
    __syncthreads();
    int p = 9;
    for (int r = 0; r < 10; ++r) {
        unsigned long long cand_k = (p >= 0) ? lv[tid * 10 + p] : 0ull;
        unsigned long long w = cand_k;
#pragma unroll
        for (int s = 32; s > 0; s >>= 1) {
            unsigned long long o = __shfl_xor(w, s, 64);
            w = (o > w) ? o : w;
        }
        if ((tid & 63) == 0) warp_r[tid >> 6] = w;
        __syncthreads();
        if (tid == 0) {
            unsigned long long ww = warp_r[0];
            ww = (warp_r[1] > ww) ? warp_r[1] : ww;
            ww = (warp_r[2] > ww) ? warp_r[2] : ww;
            ww = (warp_r[3] > ww) ? warp_r[3] : ww;
            winner_s = ww;
            float wv = __uint_as_float((unsigned)(ww >> 32));
            if (wv > TEPS) {
                unsigned wi = 0xFFFFFFFFu - (unsigned)(ww & 0xFFFFFFFFull);
                atomicOr(&selmask[(size_t)b * Nv + wi], 1u << m);
            }
        }
        __syncthreads();
        unsigned long long win = winner_s;
        if (win == 0ull) break;  // no more positive candidates
        if (p >= 0 && cand_k == win) --p;  // unique owner (idx embedded in key)
        __syncthreads();
    }
}

// ---- kernel: resolve multi-assignment (lazy bestm), per-anchor gt/align/ciou ----
__global__ __launch_bounds__(256) void k_resolve(const float* __restrict__ cls,
                                                 const float* __restrict__ bdec,
                                                 const float* __restrict__ tgt,
                                                 const float* __restrict__ anc,
                                                 const unsigned* __restrict__ selmask,
                                                 int* __restrict__ gtf,
                                                 float* __restrict__ amv,
                                                 float* __restrict__ crv,
                                                 unsigned* __restrict__ pos_al,
                                                 unsigned* __restrict__ pos_ov, int Nv) {
    __shared__ float sx1[MGT], sy1[MGT], sx2[MGT], sy2[MGT];
    __shared__ float swh[MGT], satan[MGT];
    __shared__ int slab[MGT], svld[MGT];
    int b = blockIdx.y, tid = threadIdx.x;
    if (tid < MGT) {
        const float* t = tgt + ((size_t)b * MGT + tid) * 5;
        float lf = t[0];
        float x1 = t[1], y1 = t[2], x2 = t[3], y2 = t[4];
        sx1[tid] = x1; sy1[tid] = y1; sx2[tid] = x2; sy2[tid] = y2;
        float gw = x2 - x1, gh = y2 - y1;
        swh[tid] = gw * gh;
        satan[tid] = atanf(gw / (gh + CEPS));
        float area = fmaxf(gw, 0.f) * fmaxf(gh, 0.f);
        int lab = (int)lf;
        svld[tid] = (lab >= 0 && area > 0.f) ? 1 : 0;
        slab[tid] = lab < 0 ? 0 : lab;
    }
    __syncthreads();
    int n = blockIdx.x * 256 + tid;
    if (n >= Nv) return;
    size_t bn = (size_t)b * Nv + n;
    unsigned msk = selmask[bn];
    if (!msk) { gtf[bn] = -1; amv[bn] = 0.f; crv[bn] = 0.f; return; }
    float4 p = reinterpret_cast<const float4*>(bdec)[bn];
    float pw = p.z - p.x, ph = p.w - p.y;
    float pwh = pw * ph;
    float patan = atanf(pw / (ph + CEPS));
    int g;
    if (__popc(msk) > 1) {
        // lazy best = argmax_m clip(ciou,0), first-max tiebreak (unmasked)
        float bo = -1.f; g = 0;
        for (int m = 0; m < MGT; ++m) {
            float ov = fmaxf(ciou_pre(sx1[m], sy1[m], sx2[m], sy2[m],
                                      swh[m], satan[m],
                                      p.x, p.y, p.z, p.w, pwh, patan), 0.f);
            if (ov > bo) { bo = ov; g = m; }
        }
    } else {
        g = __ffs(msk) - 1;
    }
    float cr = ciou_pre(sx1[g], sy1[g], sx2[g], sy2[g], swh[g], satan[g],
                        p.x, p.y, p.z, p.w, pwh, patan);
    float ov = fmaxf(cr, 0.f);
    float al = 0.f;
    if (svld[g]) {
        float2 a = reinterpret_cast<const float2*>(anc)[n];
        float mn = fminf(fminf(a.x - sx1[g], a.y - sy1[g]),
                         fminf(sx2[g] - a.x, sy2[g] - a.y));
        if (mn > TEPS && ov > 0.f) {
            float s = sigm_fast(cls[bn * NCLS + slab[g]]);
            float o2 = ov * ov;
            al = __builtin_sqrtf(s) * o2 * o2 * o2;
        }
    }
    gtf[bn] = g; amv[bn] = al; crv[bn] = cr;
    atomicMax(&pos_al[b * MGT + g], __float_as_uint(al));
    atomicMax(&pos_ov[b * MGT + g], __float_as_uint(ov));
}

// ---- kernel: norm (tval), tlab, tss, IoU loss, DFL loss partials ----
__global__ __launch_bounds__(256) void k_boxdfl(const float* __restrict__ bdist,
                                                const float* __restrict__ tgt,
                                                const float* __restrict__ anc,
                                                const float* __restrict__ strd,
                                                const int* __restrict__ gtf,
                                                const float* __restrict__ amv,
                                                const float* __restrict__ crv,
                                                const unsigned* __restrict__ pos_al,
                                                const unsigned* __restrict__ pos_ov,
                                                float* __restrict__ tval,
                                                int* __restrict__ tlabv,
                                                float* __restrict__ p_tss,
                                                float* __restrict__ p_iou,
                                                float* __restrict__ p_dfl, int Nv) {
    __shared__ float sx1[MGT], sy1[MGT], sx2[MGT], sy2[MGT];
    __shared__ int slab[MGT];
    __shared__ float r0[256], r1[256], r2[256];
    int b = blockIdx.y, tid = threadIdx.x;
    if (tid < MGT) {
        const float* t = tgt + ((size_t)b * MGT + tid) * 5;
        float lf = t[0];
        sx1[tid] = t[1]; sy1[tid] = t[2]; sx2[tid] = t[3]; sy2[tid] = t[4];
        slab[tid] = lf < 0.f ? 0 : (int)lf;
    }
    __syncthreads();
    int n = blockIdx.x * 256 + tid;
    float c_t = 0.f, c_i = 0.f, c_d = 0.f;
    if (n < Nv) {
        size_t bn = (size_t)b * Nv + n;
        int g = gtf[bn];
        float nv = 0.f;
        if (g >= 0) {
            float pa = __uint_as_float(pos_al[b * MGT + g]);
            float po = __uint_as_float(pos_ov[b * MGT + g]);
            nv = amv[bn] * po / (pa + TEPS);
        }
        tval[bn] = nv;
        tlabv[bn] = (g >= 0) ? slab[g] : -1;
        if (nv > 0.f) {
            c_t = nv;
            c_i = (1.f - crv[bn]) * nv;
            float2 a = reinterpret_cast<const float2*>(anc)[n];
            float st = strd[n];
            float ttv[4];
            ttv[0] = (a.x - sx1[g]) / st;
            ttv[1] = (a.y - sy1[g]) / st;
            ttv[2] = (sx2[g] - a.x) / st;
            ttv[3] = (sy2[g] - a.y) / st;
            const float* bd = bdist + bn * 64;
            float acc = 0.f;
#pragma unroll
            for (int k = 0; k < 4; ++k) {
                float t = fminf(fmaxf(ttv[k], 0.f), 14.99f);
                int tl = (int)t;
                float wl = (float)(tl + 1) - t;
                float mx = -3.4e38f;
                for (int j = 0; j < 16; ++j) mx = fmaxf(mx, bd[k * 16 + j]);
                float se = 0.f;
                for (int j = 0; j < 16; ++j) se += __expf(bd[k * 16 + j] - mx);
                float lse = mx + __logf(se);
                float ll = bd[k * 16 + tl] - lse;
                float lr = bd[k * 16 + tl + 1] - lse;
                acc += ll * wl + lr * (1.f - wl);
            }
            c_d = (-acc * 0.25f) * nv;
        }
    }
    r0[tid] = c_t; r1[tid] = c_i; r2[tid] = c_d;
    __syncthreads();
    for (int s = 128; s > 0; s >>= 1) {
        if (tid < s) { r0[tid] += r0[tid + s]; r1[tid] += r1[tid + s]; r2[tid] += r2[tid + s]; }
        __syncthreads();
    }
    if (tid == 0) {
        int bi = blockIdx.y * gridDim.x + blockIdx.x;
        p_tss[bi] = r0[0]; p_iou[bi] = r1[0]; p_dfl[bi] = r2[0];
    }
}

// ---- kernel: BCE classification loss, flat-linear coalesced, fast math ----
__global__ __launch_bounds__(256) void k_cls2(const float* __restrict__ cls,
                                              const int* __restrict__ tlabv,
                                              const float* __restrict__ tval,
                                              float* __restrict__ p_cls,
                                              int total4, int stride_t) {
    __shared__ float rs[256];
    float sum = 0.f;
    for (int i4 = blockIdx.x * 256 + threadIdx.x; i4 < total4; i4 += stride_t) {
        int bn = i4 / 20;  // 20 float4 per 80-class row
        int pos = i4 - bn * 20;
        float4 x4 = reinterpret_cast<const float4*>(cls)[i4];
        int tlab = tlabv[bn];
        float tv = tval[bn];
        int c0 = pos * 4;
        float xs[4] = {x4.x, x4.y, x4.z, x4.w};
#pragma unroll
        for (int e = 0; e < 4; ++e) {
            float x = xs[e];
            float ea = __expf(-fabsf(x));        // shared: sigmoid + log1p
            float r = __builtin_amdgcn_rcpf(1.f + ea);
            float p = (x >= 0.f) ? r : ea * r;   // sigmoid(x)
            float t = (c0 + e == tlab) ? tv : 0.f;
            float bce = fmaxf(x, 0.f) - x * t + __logf(1.f + ea);
            float w = (t > 0.f) ? t : 0.75f * p * p;
            sum += bce * w;
        }
    }
    rs[threadIdx.x] = sum;
    __syncthreads();
    for (int s = 128; s > 0; s >>= 1) {
        if (threadIdx.x < s) rs[threadIdx.x] += rs[threadIdx.x + s];
        __syncthreads();
    }
    if (threadIdx.x == 0) p_cls[blockIdx.x] = rs[0];
}

// ---- kernel: deterministic final reduce + combine ----
__global__ __launch_bounds__(256) void k_final(const float* __restrict__ p_tss,
                                               const float* __restrict__ p_iou,
                                               const float* __restrict__ p_dfl,
                                               int nb,
                                               const float* __restrict__ p_cls,
                                               int ncb, float* __restrict__ out, int Bv) {
    __shared__ float s0[256], s1[256], s2[256], s3[256];
    int tid = threadIdx.x;
    float a0 = 0.f, a1 = 0.f, a2 = 0.f, a3 = 0.f;
    for (int i = tid; i < nb; i += 256) {
        a0 += p_tss[i]; a1 += p_iou[i]; a2 += p_dfl[i];
    }
    for (int i = tid; i < ncb; i += 256) a3 += p_cls[i];
    s0[tid] = a0; s1[tid] = a1; s2[tid] = a2; s3[tid] = a3;
    __syncthreads();
    for (int s = 128; s > 0; s >>= 1) {
        if (tid < s) { s0[tid] += s0[tid + s]; s1[tid] += s1[tid + s];
                       s2[tid] += s2[tid + s]; s3[tid] += s3[tid + s]; }
        __syncthreads();
    }
    if (tid == 0) {
        float tss = fmaxf(s0[0], 1.f);
        float lcls = 0.5f * s3[0] / tss;
        float liou = 7.5f * s1[0] / tss;
        float ldfl = 1.5f * s2[0] / tss;
        out[0] = (lcls + liou + ldfl) * (float)Bv;
        out[1] = lcls;
        out[2] = liou;
        out[3] = ldfl;
    }
}

extern "C" void kernel_launch(void* const* d_in, const int* in_sizes, int n_in,
                              void* d_out, int out_size, void* d_ws, size_t ws_size,
                              hipStream_t stream) {
    const float* cls = (const float*)d_in[0];
    const float* bdist = (const float*)d_in[1];
    const float* bdec = (const float*)d_in[2];
    const float* tgt = (const float*)d_in[3];
    const float* anc = (const float*)d_in[4];
    const float* strd = (const float*)d_in[5];
    int Nv = in_sizes[4] / 2;
    int Bv = in_sizes[3] / (MGT * 5);
    size_t nBN = (size_t)Bv * Nv;
    int gx = (Nv + 255) / 256;
    int nb = gx * Bv;
    int nbm = Bv * MGT;
    int total4 = (int)(nBN * (NCLS / 4));
    int ncb = 2048;
    if ((long long)ncb * 256 > (long long)total4) ncb = (total4 + 255) / 256;

    char* base = (char*)d_ws;
    size_t off = 0;
    unsigned* selmask = (unsigned*)(base + off); off += nBN * 4;
    unsigned* pos_al = (unsigned*)(base + off); off += (size_t)nbm * 4;
    unsigned* pos_ov = (unsigned*)(base + off); off += (size_t)nbm * 4;
    unsigned* cntv = (unsigned*)(base + off); off += (size_t)nbm * 4;
    int* gtfv = (int*)(base + off); off += nBN * 4;
    float* amv = (float*)(base + off); off += nBN * 4;
    float* crvv = (float*)(base + off); off += nBN * 4;
    float* tvalv = (float*)(base + off); off += nBN * 4;
    int* tlabv = (int*)(base + off); off += nBN * 4;
    float* p_tss = (float*)(base + off); off += (size_t)nb * 4;
    float* p_iou = (float*)(base + off); off += (size_t)nb * 4;
    float* p_dfl = (float*)(base + off); off += (size_t)nb * 4;
    float* p_cls = (float*)(base + off); off += (size_t)ncb * 4;
    off = (off + 7) & ~(size_t)7;  // align for u64
    unsigned long long* cand = (unsigned long long*)(base + off);
    size_t remain = (ws_size > off) ? (ws_size - off) : 0;
    int cap = (int)(remain / ((size_t)nbm * 8));
    if (cap > CAPMAX) cap = CAPMAX;
    if (cap < 1) cap = 1;

    dim3 grid(gx, Bv);
    hipMemsetAsync(cntv, 0, (size_t)nbm * 4, stream);
    k_cand<<<grid, 256, 0, stream>>>(cls, bdec, tgt, anc, cand, cntv,
                                     selmask, pos_al, pos_ov, Nv, cap);
    k_topk2<<<nbm, 256, 0, stream>>>(cand, cntv, selmask, Nv, cap);
    k_resolve<<<grid, 256, 0, stream>>>(cls, bdec, tgt, anc, selmask,
                                        gtfv, amv, crvv, pos_al, pos_ov, Nv);
    k_boxdfl<<<grid, 256, 0, stream>>>(bdist, tgt, anc, strd, gtfv, amv, crvv,
                                       pos_al, pos_ov, tvalv, tlabv,
                                       p_tss, p_iou, p_dfl, Nv);
    k_cls2<<<ncb, 256, 0, stream>>>(cls, tlabv, tvalv, p_cls, total4, ncb * 256);
    k_final<<<1, 256, 0, stream>>>(p_tss, p_iou, p_dfl, nb, p_cls, ncb,
                                   (float*)d_out, Bv);
}